// Round 1
// baseline (102.144 us; speedup 1.0000x reference)
//
#include <hip/hip_runtime.h>

#define BATCH 16
#define INCH  64
#define IMH   128
#define IMW   128
#define OUTCH 128
#define SUB   8
#define OH    126
#define OW    126

// spatial tile per block
#define YT 8
#define XT 16
#define TR (YT + 2)        // 10 input rows
#define RS 20              // LDS row stride (floats); 18 used + 2 pad
#define CHS (TR * RS)      // 200 floats per channel

__global__ __launch_bounds__(256, 3)
void Group_Conv_84731114815961_kernel(const float* __restrict__ X,
                                      const float* __restrict__ Wg,
                                      const float* __restrict__ Bias,
                                      float* __restrict__ Out) {
    __shared__ float xin[INCH * CHS];   // 64 * 200 * 4B = 51200 B

    const int tx  = blockIdx.x;   // 0..7   (x tiles)
    const int ty  = blockIdx.y;   // 0..15  (y tiles)
    const int b   = blockIdx.z;   // 0..15  (batch)
    const int x0  = tx * XT;
    const int y0  = ty * YT;
    const int tid = threadIdx.x;

    // ---- stage input tile: 64 ch x 10 rows x 18 cols (stride 20) ----
    const float* Xb = X + (size_t)b * INCH * IMH * IMW;
    #pragma unroll
    for (int it = 0; it < (INCH * CHS / 4 + 255) / 256; ++it) {
        int k = tid + it * 256;
        if (k < INCH * CHS / 4) {
            int fi  = k * 4;
            int c   = fi / CHS;
            int rem = fi - c * CHS;
            int r   = rem / RS;
            int col = rem - r * RS;          // 0,4,8,12,16
            int sr = y0 + r;  if (sr > IMH - 1) sr = IMH - 1;
            int sc = x0 + col; if (sc > IMW - 4) sc = IMW - 4;
            const float4 v = *reinterpret_cast<const float4*>(Xb + (c * IMH + sr) * IMW + sc);
            *reinterpret_cast<float4*>(&xin[fi]) = v;
        }
    }
    __syncthreads();

    const int p  = tid >> 2;   // o-pair index 0..63  (o = p and p+64)
    const int xg = tid & 3;    // x group 0..3
    const int cb = xg * 4;     // tile col base

    float acc0[YT][4];
    float acc1[YT][4];
    #pragma unroll
    for (int y = 0; y < YT; ++y)
        #pragma unroll
        for (int q = 0; q < 4; ++q) { acc0[y][q] = 0.f; acc1[y][q] = 0.f; }

    for (int s = 0; s < SUB; ++s) {
        const int c = (p + s) & 63;
        const float* w0p = Wg + (p * SUB + s) * 9;
        const float* w1p = Wg + ((p + 64) * SUB + s) * 9;
        float w0[9], w1[9];
        #pragma unroll
        for (int t = 0; t < 9; ++t) { w0[t] = w0p[t]; w1[t] = w1p[t]; }

        const float* base = &xin[c * CHS + cb];
        #pragma unroll
        for (int r = 0; r < TR; ++r) {
            float v[6];
            const float4 a  = *reinterpret_cast<const float4*>(base + r * RS);
            const float2 b2 = *reinterpret_cast<const float2*>(base + r * RS + 4);
            v[0] = a.x; v[1] = a.y; v[2] = a.z; v[3] = a.w; v[4] = b2.x; v[5] = b2.y;
            #pragma unroll
            for (int i = 0; i < 3; ++i) {
                const int yo = r - i;
                if (yo >= 0 && yo < YT) {
                    #pragma unroll
                    for (int j = 0; j < 3; ++j) {
                        const float ww0 = w0[i * 3 + j];
                        const float ww1 = w1[i * 3 + j];
                        #pragma unroll
                        for (int q = 0; q < 4; ++q) {
                            acc0[yo][q] = fmaf(v[q + j], ww0, acc0[yo][q]);
                            acc1[yo][q] = fmaf(v[q + j], ww1, acc1[yo][q]);
                        }
                    }
                }
            }
        }
    }

    // ---- epilogue: bias + masked stores ----
    const float bz0 = Bias[p];
    const float bz1 = Bias[p + 64];
    const int   xcol = x0 + cb;
    float* O0 = Out + (((size_t)b * OUTCH + p)      * OH) * OW;
    float* O1 = Out + (((size_t)b * OUTCH + p + 64) * OH) * OW;

    #pragma unroll
    for (int y = 0; y < YT; ++y) {
        const int oy = y0 + y;
        if (oy < OH) {
            float* o0 = O0 + oy * OW + xcol;
            float* o1 = O1 + oy * OW + xcol;
            if (xcol + 3 < OW) {
                float4 s0, s1;
                s0.x = acc0[y][0] + bz0; s0.y = acc0[y][1] + bz0;
                s0.z = acc0[y][2] + bz0; s0.w = acc0[y][3] + bz0;
                s1.x = acc1[y][0] + bz1; s1.y = acc1[y][1] + bz1;
                s1.z = acc1[y][2] + bz1; s1.w = acc1[y][3] + bz1;
                *reinterpret_cast<float4*>(o0) = s0;
                *reinterpret_cast<float4*>(o1) = s1;
            } else {
                #pragma unroll
                for (int q = 0; q < 4; ++q) {
                    if (xcol + q < OW) {
                        o0[q] = acc0[y][q] + bz0;
                        o1[q] = acc1[y][q] + bz1;
                    }
                }
            }
        }
    }
}

extern "C" void kernel_launch(void* const* d_in, const int* in_sizes, int n_in,
                              void* d_out, int out_size, void* d_ws, size_t ws_size,
                              hipStream_t stream) {
    const float* X    = (const float*)d_in[0];
    const float* Wg   = (const float*)d_in[1];
    const float* Bias = (const float*)d_in[2];
    float*       Out  = (float*)d_out;

    dim3 grid(8, 16, 16);   // x-tiles, y-tiles, batch
    Group_Conv_84731114815961_kernel<<<grid, 256, 0, stream>>>(X, Wg, Bias, Out);
}